// Round 3
// baseline (210106.421 us; speedup 1.0000x reference)
//
#include <hip/hip_runtime.h>
#include <stdint.h>
#include <math.h>

#define NBLK 128
#define NTHR 256
#define Bn 16
#define Tn 2000
#define Cn 128
#define Gn 512
#define Hn 512
#define Vn 256

// workspace layout in DOUBLES. First 64 doubles (512 B) reserved for barrier.
#define DX    64                    // X: [16,128]
#define DH    (DX + Bn*Cn)          // H ping-pong: 2*[16,512]
#define DRZ   (DH + 2*Bn*Gn)        // sigmoid(r),sigmoid(z): [16,1024]
#define DHN   (DRZ + Bn*1024)       // h_n preact: [16,512]
#define DIN   (DHN + Bn*Gn)         // i_n preact: [16,512]
#define DHID  (DIN + Bn*Gn)         // relu hidden: [16,512]

#define OUT_SAMP ((size_t)Bn*Tn*Vn)          // 8,192,000
#define OUT_HF   (OUT_SAMP + (size_t)Bn*Tn)  // 8,224,000

__device__ __forceinline__ unsigned rotl32(unsigned v, int n) {
  return (v << n) | (v >> (32 - n));
}

// JAX threefry2x32, 20 rounds, exact.
__device__ __forceinline__ void threefry2x32(unsigned k0, unsigned k1,
                                             unsigned c0, unsigned c1,
                                             unsigned& o0, unsigned& o1) {
  unsigned ks2 = k0 ^ k1 ^ 0x1BD11BDAu;
  unsigned x0 = c0 + k0;
  unsigned x1 = c1 + k1;
#define TF_R(r) { x0 += x1; x1 = rotl32(x1, r); x1 ^= x0; }
  TF_R(13) TF_R(15) TF_R(26) TF_R(6)
  x0 += k1;  x1 += ks2 + 1u;
  TF_R(17) TF_R(29) TF_R(16) TF_R(24)
  x0 += ks2; x1 += k0 + 2u;
  TF_R(13) TF_R(15) TF_R(26) TF_R(6)
  x0 += k0;  x1 += k1 + 3u;
  TF_R(17) TF_R(29) TF_R(16) TF_R(24)
  x0 += k1;  x1 += ks2 + 4u;
  TF_R(13) TF_R(15) TF_R(26) TF_R(6)
  x0 += ks2; x1 += k0 + 5u;
#undef TF_R
  o0 = x0; o1 = x1;
}

// device-scope grid barrier; bar[0]=count, bar[1]=generation.
__device__ __forceinline__ void gbar(unsigned* bar) {
  __syncthreads();
  if (threadIdx.x == 0) {
    unsigned g = __hip_atomic_load(&bar[1], __ATOMIC_RELAXED, __HIP_MEMORY_SCOPE_AGENT);
    unsigned arrived = __hip_atomic_fetch_add(&bar[0], 1u, __ATOMIC_ACQ_REL,
                                              __HIP_MEMORY_SCOPE_AGENT);
    if (arrived == (unsigned)(NBLK - 1)) {
      __hip_atomic_store(&bar[0], 0u, __ATOMIC_RELAXED, __HIP_MEMORY_SCOPE_AGENT);
      __hip_atomic_fetch_add(&bar[1], 1u, __ATOMIC_RELEASE, __HIP_MEMORY_SCOPE_AGENT);
    } else {
      int guard = 0;
      while (__hip_atomic_load(&bar[1], __ATOMIC_ACQUIRE,
                               __HIP_MEMORY_SCOPE_AGENT) == g) {
        if (++guard > 50000000) break;  // safety: never hang the bench
      }
    }
  }
  __syncthreads();
}

extern "C" __global__ __launch_bounds__(NTHR)
void wavernn_persist(const float* __restrict__ cond, const float* __restrict__ h0,
                     const float* __restrict__ W_ih, const float* __restrict__ W_hh,
                     const float* __restrict__ b_ih, const float* __restrict__ b_hh,
                     const float* __restrict__ W_hid, const float* __restrict__ b_hid,
                     const float* __restrict__ W_out, const float* __restrict__ b_out,
                     const float* __restrict__ emb,
                     float* __restrict__ out, double* __restrict__ ws) {
  unsigned* bar = (unsigned*)ws;
  double* X    = ws + DX;
  double* Hbuf = ws + DH;
  double* RZ   = ws + DRZ;
  double* HN   = ws + DHN;
  double* IN   = ws + DIN;
  double* HIDW = ws + DHID;

  const int tid = threadIdx.x;
  const int blk = blockIdx.x;
  const unsigned gid = (unsigned)blk * NTHR + tid;

  __shared__ double s_xh[Cn + Gn];   // phase A: [x | h]
  __shared__ double s_h[Gn];         // phase B: h_new ; phase C: hid
  __shared__ double s_red[NTHR];
  __shared__ int    s_idx[NTHR];

  // ---- init: h = h0 (buffer 0), x = cond[:,0,:] + emb[128] ----
  if (gid < (unsigned)(Bn * Gn)) Hbuf[gid] = (double)h0[gid];
  if (gid >= (unsigned)(Bn * Gn) && gid < (unsigned)(Bn * Gn + Bn * Cn)) {
    unsigned i = gid - (unsigned)(Bn * Gn);
    unsigned b = i >> 7, c = i & 127u;
    X[i] = (double)cond[(size_t)b * Tn * Cn + c] + (double)emb[128 * Cn + c];
  }
  gbar(bar);

  for (int t = 0; t < Tn; ++t) {
    // ================= Phase A: gate dots (all 128 blocks) =================
    {
      const unsigned b = gid >> 11;        // block-uniform
      const unsigned j = gid & 2047u;      // 256-aligned slice per block
      const double* Hin = Hbuf + (size_t)(t & 1) * Bn * Gn + (size_t)b * Gn;
      for (int i = tid; i < Cn + Gn; i += NTHR)
        s_xh[i] = (i < Cn) ? X[b * Cn + i] : Hin[i - Cn];
      __syncthreads();
      const double4* x4 = (const double4*)s_xh;
      const double4* h4 = (const double4*)(s_xh + Cn);

      if (j < 1024u) {
        const int row = (int)j;
        const float4* wi = (const float4*)(W_ih + (size_t)row * Cn);
        const float4* wh = (const float4*)(W_hh + (size_t)row * Gn);
        double a0 = 0., a1 = 0., a2 = 0., a3 = 0.;
#pragma unroll 8
        for (int k = 0; k < Cn / 4; ++k) {
          float4 w = wi[k]; double4 xv = x4[k];
          a0 = fma((double)w.x, xv.x, a0); a1 = fma((double)w.y, xv.y, a1);
          a2 = fma((double)w.z, xv.z, a2); a3 = fma((double)w.w, xv.w, a3);
        }
#pragma unroll 8
        for (int k = 0; k < Gn / 4; ++k) {
          float4 w = wh[k]; double4 hv = h4[k];
          a0 = fma((double)w.x, hv.x, a0); a1 = fma((double)w.y, hv.y, a1);
          a2 = fma((double)w.z, hv.z, a2); a3 = fma((double)w.w, hv.w, a3);
        }
        double pre = ((a0 + a1) + (a2 + a3)) + (double)b_ih[row] + (double)b_hh[row];
        RZ[b * 1024u + j] = 1.0 / (1.0 + exp(-pre));
      } else if (j < 1536u) {
        const int g = (int)j - 1024;
        const int row = 1024 + g;
        const float4* wh = (const float4*)(W_hh + (size_t)row * Gn);
        double a0 = 0., a1 = 0., a2 = 0., a3 = 0.;
#pragma unroll 8
        for (int k = 0; k < Gn / 4; ++k) {
          float4 w = wh[k]; double4 hv = h4[k];
          a0 = fma((double)w.x, hv.x, a0); a1 = fma((double)w.y, hv.y, a1);
          a2 = fma((double)w.z, hv.z, a2); a3 = fma((double)w.w, hv.w, a3);
        }
        HN[b * Gn + g] = ((a0 + a1) + (a2 + a3)) + (double)b_hh[row];
      } else {
        const int g = (int)j - 1536;
        const int row = 1024 + g;
        const float4* wi = (const float4*)(W_ih + (size_t)row * Cn);
        double a0 = 0., a1 = 0., a2 = 0., a3 = 0.;
#pragma unroll 8
        for (int k = 0; k < Cn / 4; ++k) {
          float4 w = wi[k]; double4 xv = x4[k];
          a0 = fma((double)w.x, xv.x, a0); a1 = fma((double)w.y, xv.y, a1);
          a2 = fma((double)w.z, xv.z, a2); a3 = fma((double)w.w, xv.w, a3);
        }
        IN[b * Gn + g] = ((a0 + a1) + (a2 + a3)) + (double)b_ih[row];
      }
    }
    gbar(bar);

    // ====== Phase B: gate combine + h update + hid (blocks 0..31) ======
    if (blk < 32) {
      const int b = blk >> 1, half = blk & 1;
      const double* Hin = Hbuf + (size_t)(t & 1) * Bn * Gn + (size_t)b * Gn;
      double* Hout = Hbuf + (size_t)((t + 1) & 1) * Bn * Gn + (size_t)b * Gn;
      for (int g = tid; g < Gn; g += NTHR) {
        double r = RZ[b * 1024 + g];
        double z = RZ[b * 1024 + 512 + g];
        double n = tanh(IN[b * Gn + g] + r * HN[b * Gn + g]);
        double hv = (1.0 - z) * n + z * Hin[g];
        s_h[g] = hv;
        if (half == 0) {
          Hout[g] = hv;
          if (t == Tn - 1) out[OUT_HF + (size_t)b * Gn + g] = (float)hv;
        }
      }
      __syncthreads();
      const int jrow = half * 256 + tid;
      const float4* wr = (const float4*)(W_hid + (size_t)jrow * Gn);
      const double4* hh = (const double4*)s_h;
      double a0 = 0., a1 = 0., a2 = 0., a3 = 0.;
#pragma unroll 8
      for (int k = 0; k < Gn / 4; ++k) {
        float4 w = wr[k]; double4 hv = hh[k];
        a0 = fma((double)w.x, hv.x, a0); a1 = fma((double)w.y, hv.y, a1);
        a2 = fma((double)w.z, hv.z, a2); a3 = fma((double)w.w, hv.w, a3);
      }
      double acc = ((a0 + a1) + (a2 + a3)) + (double)b_hid[jrow];
      HIDW[b * Hn + jrow] = acc > 0.0 ? acc : 0.0;
    }
    gbar(bar);

    // ====== Phase C: logits + JAX partitionable-threefry gumbel argmax ======
    if (blk < 16) {
      const int b = blk;
      for (int k = tid; k < Hn; k += NTHR) s_h[k] = HIDW[b * Hn + k];
      __syncthreads();
      const int v = tid;  // Vn == NTHR == 256
      const float4* wr = (const float4*)(W_out + (size_t)v * Hn);
      const double4* hh = (const double4*)s_h;
      double a0 = 0., a1 = 0., a2 = 0., a3 = 0.;
#pragma unroll 8
      for (int k = 0; k < Hn / 4; ++k) {
        float4 w = wr[k]; double4 hv = hh[k];
        a0 = fma((double)w.x, hv.x, a0); a1 = fma((double)w.y, hv.y, a1);
        a2 = fma((double)w.z, hv.z, a2); a3 = fma((double)w.w, hv.w, a3);
      }
      double logit = ((a0 + a1) + (a2 + a3)) + (double)b_out[v];
      out[(size_t)b * Tn * Vn + (size_t)t * Vn + v] = (float)logit;

      // --- JAX threefry PARTITIONABLE mode (default since jax 0.4.36) ---
      // split(key(1)=(0,1), T) foldlike: keys[t] = threefry2x32((0,1),(0,t))
      unsigned kt0, kt1;
      threefry2x32(0u, 1u, 0u, (unsigned)t, kt0, kt1);
      // random_bits(keys[t], 32, (16,256)): elem f -> o0^o1 of
      //   threefry2x32(keys[t], (hi64=0, lo64=f))
      unsigned f = (unsigned)(b * Vn + v);
      unsigned r0, r1;
      threefry2x32(kt0, kt1, 0u, f, r0, r1);
      unsigned bits = r0 ^ r1;
      float uf = __uint_as_float((bits >> 9) | 0x3f800000u) - 1.0f;
      if (uf <= 0.f) uf = 1.17549435e-38f;  // np.finfo(float32).tiny
      double gum = -log(-log((double)uf));
      s_red[tid] = logit + gum;
      s_idx[tid] = v;
      __syncthreads();
      for (int s2 = NTHR / 2; s2 > 0; s2 >>= 1) {
        if (tid < s2) {
          double ov = s_red[tid + s2]; int oi = s_idx[tid + s2];
          if (ov > s_red[tid] || (ov == s_red[tid] && oi < s_idx[tid])) {
            s_red[tid] = ov; s_idx[tid] = oi;
          }
        }
        __syncthreads();
      }
      const int samp = s_idx[0];
      if (tid == 0) out[OUT_SAMP + (size_t)b * Tn + t] = (float)samp;
      if (t + 1 < Tn && tid < Cn) {
        X[b * Cn + tid] = (double)cond[((size_t)b * Tn + (t + 1)) * Cn + tid]
                        + (double)emb[(size_t)samp * Cn + tid];
      }
    }
    gbar(bar);
  }
}

extern "C" void kernel_launch(void* const* d_in, const int* in_sizes, int n_in,
                              void* d_out, int out_size, void* d_ws, size_t ws_size,
                              hipStream_t stream) {
  const float* cond  = (const float*)d_in[0];
  const float* h0    = (const float*)d_in[1];
  const float* W_ih  = (const float*)d_in[2];
  const float* W_hh  = (const float*)d_in[3];
  const float* b_ih  = (const float*)d_in[4];
  const float* b_hh  = (const float*)d_in[5];
  const float* W_hid = (const float*)d_in[6];
  const float* b_hid = (const float*)d_in[7];
  const float* W_out = (const float*)d_in[8];
  const float* b_out = (const float*)d_in[9];
  const float* emb   = (const float*)d_in[10];

  // zero the barrier region (ws is poisoned 0xAA before every call)
  hipMemsetAsync(d_ws, 0, 512, stream);
  hipLaunchKernelGGL(wavernn_persist, dim3(NBLK), dim3(NTHR), 0, stream,
                     cond, h0, W_ih, W_hh, b_ih, b_hh, W_hid, b_hid,
                     W_out, b_out, emb, (float*)d_out, (double*)d_ws);
}

// Round 4
// 94988.617 us; speedup vs baseline: 2.2119x; 2.2119x over previous
//
#include <hip/hip_runtime.h>
#include <stdint.h>
#include <math.h>

#define NBLK 128
#define NTHR 256
#define Bn 16
#define Tn 2000
#define Cn 128
#define Gn 512
#define Hn 512
#define Vn 256

// ws layout: first 4096 B = flag array (16 groups x 64 u32, 256 B apart).
// Then doubles: per group 2048 doubles: H0[0,512) H1[512,1024) HID[1024,1536)
// PV[1536,1544) PI[1544,1552).
#define WS_DBL_BASE 512   // in doubles (= 4096 B)
#define GRP_STRIDE  2048

#define OUT_SAMP ((size_t)Bn*Tn*Vn)          // 8,192,000
#define OUT_HF   (OUT_SAMP + (size_t)Bn*Tn)  // 8,224,000

__device__ __forceinline__ unsigned rotl32(unsigned v, int n) {
  return (v << n) | (v >> (32 - n));
}

// JAX threefry2x32, 20 rounds, exact.
__device__ __forceinline__ void threefry2x32(unsigned k0, unsigned k1,
                                             unsigned c0, unsigned c1,
                                             unsigned& o0, unsigned& o1) {
  unsigned ks2 = k0 ^ k1 ^ 0x1BD11BDAu;
  unsigned x0 = c0 + k0;
  unsigned x1 = c1 + k1;
#define TF_R(r) { x0 += x1; x1 = rotl32(x1, r); x1 ^= x0; }
  TF_R(13) TF_R(15) TF_R(26) TF_R(6)
  x0 += k1;  x1 += ks2 + 1u;
  TF_R(17) TF_R(29) TF_R(16) TF_R(24)
  x0 += ks2; x1 += k0 + 2u;
  TF_R(13) TF_R(15) TF_R(26) TF_R(6)
  x0 += k0;  x1 += k1 + 3u;
  TF_R(17) TF_R(29) TF_R(16) TF_R(24)
  x0 += k1;  x1 += ks2 + 4u;
  TF_R(13) TF_R(15) TF_R(26) TF_R(6)
  x0 += ks2; x1 += k0 + 5u;
#undef TF_R
  o0 = x0; o1 = x1;
}

// 8-way group barrier: store-release own slot, spin-acquire on all 8 slots.
// Monotone target -> no reset, no RMW contention.
__device__ __forceinline__ void gbar8(unsigned* flags, int slot, unsigned target) {
  __syncthreads();
  if (threadIdx.x == 0)
    __hip_atomic_store(&flags[slot], target, __ATOMIC_RELEASE,
                       __HIP_MEMORY_SCOPE_AGENT);
  if (threadIdx.x < 8) {
    int guard = 0;
    while (__hip_atomic_load(&flags[threadIdx.x], __ATOMIC_ACQUIRE,
                             __HIP_MEMORY_SCOPE_AGENT) < target) {
      if (++guard > 50000000) break;  // safety: never hang the bench
    }
  }
  __syncthreads();
}

extern "C" __global__ __launch_bounds__(NTHR)
void wavernn_groups(const float* __restrict__ cond, const float* __restrict__ h0,
                    const float* __restrict__ W_ih, const float* __restrict__ W_hh,
                    const float* __restrict__ b_ih, const float* __restrict__ b_hh,
                    const float* __restrict__ W_hid, const float* __restrict__ b_hid,
                    const float* __restrict__ W_out, const float* __restrict__ b_out,
                    const float* __restrict__ emb,
                    float* __restrict__ out, double* __restrict__ ws) {
  const int tid = threadIdx.x;
  const int blk = blockIdx.x;
  const int g = blk >> 3;   // batch element (group)
  const int j = blk & 7;    // slot within group (lands on XCD j for all groups)

  unsigned* flags = ((unsigned*)ws) + (size_t)g * 64;
  double* G   = ws + WS_DBL_BASE + (size_t)g * GRP_STRIDE;
  double* Hb0 = G;
  double* Hb1 = G + 512;
  double* HID = G + 1024;
  double* PV  = G + 1536;
  double* PI  = G + 1544;

  __shared__ __attribute__((aligned(32))) double s_x[Cn];
  __shared__ __attribute__((aligned(32))) double s_h[Gn];
  __shared__ double s_r[64], s_z[64], s_hn[64], s_in[64];
  __shared__ double s_red[32];
  __shared__ int    s_idx[32];
  __shared__ double s_pv[8];
  __shared__ int    s_pi[8];
  __shared__ int    s_samp;

  // ---- init: H0 slice <- h0; x0 = cond[:,0,:] + emb[128] (local LDS) ----
  if (tid < 64) Hb0[j * 64 + tid] = (double)h0[(size_t)g * Gn + j * 64 + tid];
  if (tid < Cn) s_x[tid] = (double)cond[(size_t)g * Tn * Cn + tid]
                         + (double)emb[128 * Cn + tid];
  unsigned pc = 1;
  gbar8(flags, j, pc++);

  for (int t = 0; t < Tn; ++t) {
    double* hcur = (t & 1) ? Hb1 : Hb0;
    double* hnxt = (t & 1) ? Hb0 : Hb1;

    // ============ Phase A: gate dots + combine (own g-slice) ============
    for (int i = tid; i < Gn; i += NTHR) s_h[i] = hcur[i];
    __syncthreads();
    {
      const int part = tid >> 6, gl = tid & 63;
      const double4* x4 = (const double4*)s_x;
      const double4* h4 = (const double4*)s_h;
      if (part <= 1) {
        // r (part 0) / z (part 1): x.Wih + h.Whh + biases -> sigmoid
        const int row = part * 512 + j * 64 + gl;
        const float4* wi = (const float4*)(W_ih + (size_t)row * Cn);
        const float4* wh = (const float4*)(W_hh + (size_t)row * Gn);
        double a0 = 0., a1 = 0., a2 = 0., a3 = 0.;
#pragma unroll 8
        for (int k = 0; k < Cn / 4; ++k) {
          float4 w = wi[k]; double4 xv = x4[k];
          a0 = fma((double)w.x, xv.x, a0); a1 = fma((double)w.y, xv.y, a1);
          a2 = fma((double)w.z, xv.z, a2); a3 = fma((double)w.w, xv.w, a3);
        }
#pragma unroll 8
        for (int k = 0; k < Gn / 4; ++k) {
          float4 w = wh[k]; double4 hv = h4[k];
          a0 = fma((double)w.x, hv.x, a0); a1 = fma((double)w.y, hv.y, a1);
          a2 = fma((double)w.z, hv.z, a2); a3 = fma((double)w.w, hv.w, a3);
        }
        double pre = ((a0 + a1) + (a2 + a3)) + (double)b_ih[row] + (double)b_hh[row];
        double sig = 1.0 / (1.0 + exp(-pre));
        if (part == 0) s_r[gl] = sig; else s_z[gl] = sig;
      } else if (part == 2) {
        // h_n preact: h . W_hh[1024+g] + b_hh
        const int row = 1024 + j * 64 + gl;
        const float4* wh = (const float4*)(W_hh + (size_t)row * Gn);
        double a0 = 0., a1 = 0., a2 = 0., a3 = 0.;
#pragma unroll 8
        for (int k = 0; k < Gn / 4; ++k) {
          float4 w = wh[k]; double4 hv = h4[k];
          a0 = fma((double)w.x, hv.x, a0); a1 = fma((double)w.y, hv.y, a1);
          a2 = fma((double)w.z, hv.z, a2); a3 = fma((double)w.w, hv.w, a3);
        }
        s_hn[gl] = ((a0 + a1) + (a2 + a3)) + (double)b_hh[row];
      } else {
        // i_n preact: x . W_ih[1024+g] + b_ih
        const int row = 1024 + j * 64 + gl;
        const float4* wi = (const float4*)(W_ih + (size_t)row * Cn);
        double a0 = 0., a1 = 0., a2 = 0., a3 = 0.;
#pragma unroll 8
        for (int k = 0; k < Cn / 4; ++k) {
          float4 w = wi[k]; double4 xv = x4[k];
          a0 = fma((double)w.x, xv.x, a0); a1 = fma((double)w.y, xv.y, a1);
          a2 = fma((double)w.z, xv.z, a2); a3 = fma((double)w.w, xv.w, a3);
        }
        s_in[gl] = ((a0 + a1) + (a2 + a3)) + (double)b_ih[row];
      }
    }
    __syncthreads();
    if (tid < 64) {
      double r = s_r[tid], z = s_z[tid];
      double n = tanh(s_in[tid] + r * s_hn[tid]);
      double hv = (1.0 - z) * n + z * s_h[j * 64 + tid];
      hnxt[j * 64 + tid] = hv;
      if (t == Tn - 1) out[OUT_HF + (size_t)g * Gn + j * 64 + tid] = (float)hv;
    }
    gbar8(flags, j, pc++);

    // ============ Phase B: hid rows [64j, 64j+64) ============
    for (int i = tid; i < Gn; i += NTHR) s_h[i] = hnxt[i];
    __syncthreads();
    if (tid < 64) {
      const int row = j * 64 + tid;
      const float4* wr = (const float4*)(W_hid + (size_t)row * Gn);
      const double4* hh = (const double4*)s_h;
      double a0 = 0., a1 = 0., a2 = 0., a3 = 0.;
#pragma unroll 8
      for (int k = 0; k < Gn / 4; ++k) {
        float4 w = wr[k]; double4 hv = hh[k];
        a0 = fma((double)w.x, hv.x, a0); a1 = fma((double)w.y, hv.y, a1);
        a2 = fma((double)w.z, hv.z, a2); a3 = fma((double)w.w, hv.w, a3);
      }
      double acc = ((a0 + a1) + (a2 + a3)) + (double)b_hid[row];
      HID[row] = acc > 0.0 ? acc : 0.0;
    }
    gbar8(flags, j, pc++);

    // ============ Phase C: logits [32j,32j+32) + gumbel + partial argmax ===
    for (int i = tid; i < Hn; i += NTHR) s_h[i] = HID[i];
    __syncthreads();
    if (tid < 32) {
      const int v = j * 32 + tid;
      const float4* wr = (const float4*)(W_out + (size_t)v * Hn);
      const double4* hh = (const double4*)s_h;
      double a0 = 0., a1 = 0., a2 = 0., a3 = 0.;
#pragma unroll 8
      for (int k = 0; k < Hn / 4; ++k) {
        float4 w = wr[k]; double4 hv = hh[k];
        a0 = fma((double)w.x, hv.x, a0); a1 = fma((double)w.y, hv.y, a1);
        a2 = fma((double)w.z, hv.z, a2); a3 = fma((double)w.w, hv.w, a3);
      }
      double logit = ((a0 + a1) + (a2 + a3)) + (double)b_out[v];
      out[(size_t)g * Tn * Vn + (size_t)t * Vn + v] = (float)logit;

      // JAX partitionable threefry: keys[t]=tf((0,1),(0,t)); bits=o0^o1 of
      // tf(keys[t],(0, b*256+v))
      unsigned kt0, kt1, r0, r1;
      threefry2x32(0u, 1u, 0u, (unsigned)t, kt0, kt1);
      threefry2x32(kt0, kt1, 0u, (unsigned)(g * Vn + v), r0, r1);
      unsigned bits = r0 ^ r1;
      float uf = __uint_as_float((bits >> 9) | 0x3f800000u) - 1.0f;
      if (uf <= 0.f) uf = 1.17549435e-38f;  // np.finfo(float32).tiny
      double gum = -log(-log((double)uf));
      s_red[tid] = logit + gum;
      s_idx[tid] = v;
    }
    __syncthreads();
    for (int s2 = 16; s2 > 0; s2 >>= 1) {
      if (tid < s2) {
        double ov = s_red[tid + s2]; int oi = s_idx[tid + s2];
        if (ov > s_red[tid] || (ov == s_red[tid] && oi < s_idx[tid])) {
          s_red[tid] = ov; s_idx[tid] = oi;
        }
      }
      __syncthreads();
    }
    if (tid == 0) { PV[j] = s_red[0]; PI[j] = (double)s_idx[0]; }
    gbar8(flags, j, pc++);

    // ---- resolve sample (all blocks, redundantly) + next x ----
    if (tid < 8) { s_pv[tid] = PV[tid]; s_pi[tid] = (int)PI[tid]; }
    __syncthreads();
    if (tid == 0) {
      double bv = s_pv[0]; int bi = s_pi[0];
#pragma unroll
      for (int q = 1; q < 8; ++q) {
        if (s_pv[q] > bv) { bv = s_pv[q]; bi = s_pi[q]; }
      }
      s_samp = bi;
      if (j == 0) out[OUT_SAMP + (size_t)g * Tn + t] = (float)bi;
    }
    __syncthreads();
    const int samp = s_samp;
    if (t + 1 < Tn && tid < Cn) {
      s_x[tid] = (double)cond[((size_t)g * Tn + (t + 1)) * Cn + tid]
               + (double)emb[(size_t)samp * Cn + tid];
    }
    // s_x writes are ordered before next phase-A reads by the __syncthreads
    // following phase-A staging.
  }
}

extern "C" void kernel_launch(void* const* d_in, const int* in_sizes, int n_in,
                              void* d_out, int out_size, void* d_ws, size_t ws_size,
                              hipStream_t stream) {
  const float* cond  = (const float*)d_in[0];
  const float* h0    = (const float*)d_in[1];
  const float* W_ih  = (const float*)d_in[2];
  const float* W_hh  = (const float*)d_in[3];
  const float* b_ih  = (const float*)d_in[4];
  const float* b_hh  = (const float*)d_in[5];
  const float* W_hid = (const float*)d_in[6];
  const float* b_hid = (const float*)d_in[7];
  const float* W_out = (const float*)d_in[8];
  const float* b_out = (const float*)d_in[9];
  const float* emb   = (const float*)d_in[10];

  // zero the flag region (ws is poisoned 0xAA before every call)
  hipMemsetAsync(d_ws, 0, 4096, stream);
  hipLaunchKernelGGL(wavernn_groups, dim3(NBLK), dim3(NTHR), 0, stream,
                     cond, h0, W_ih, W_hh, b_ih, b_hh, W_hid, b_hid,
                     W_out, b_out, emb, (float*)d_out, (double*)d_ws);
}

// Round 5
// 55516.156 us; speedup vs baseline: 3.7846x; 1.7110x over previous
//
#include <hip/hip_runtime.h>
#include <stdint.h>
#include <math.h>

#define NBLK 128
#define NTHR 256
#define Bn 16
#define Tn 2000
#define Cn 128
#define Gn 512
#define Hn 512
#define Vn 256

// ws layout: first 4096 B = flags (16 groups x 64 u32).
// Then doubles per group (stride 3072): H0[0,512) H1[512,1024) PL[1024,3072)
// where PL = 8 slots x 256 partial logits.
#define WS_DBL_BASE 512
#define GRP_STRIDE  3072

#define OUT_SAMP ((size_t)Bn*Tn*Vn)          // 8,192,000
#define OUT_HF   (OUT_SAMP + (size_t)Bn*Tn)  // 8,224,000

__device__ __forceinline__ unsigned rotl32(unsigned v, int n) {
  return (v << n) | (v >> (32 - n));
}

// JAX threefry2x32, 20 rounds, exact.
__device__ __forceinline__ void threefry2x32(unsigned k0, unsigned k1,
                                             unsigned c0, unsigned c1,
                                             unsigned& o0, unsigned& o1) {
  unsigned ks2 = k0 ^ k1 ^ 0x1BD11BDAu;
  unsigned x0 = c0 + k0;
  unsigned x1 = c1 + k1;
#define TF_R(r) { x0 += x1; x1 = rotl32(x1, r); x1 ^= x0; }
  TF_R(13) TF_R(15) TF_R(26) TF_R(6)
  x0 += k1;  x1 += ks2 + 1u;
  TF_R(17) TF_R(29) TF_R(16) TF_R(24)
  x0 += ks2; x1 += k0 + 2u;
  TF_R(13) TF_R(15) TF_R(26) TF_R(6)
  x0 += k0;  x1 += k1 + 3u;
  TF_R(17) TF_R(29) TF_R(16) TF_R(24)
  x0 += k1;  x1 += ks2 + 4u;
  TF_R(13) TF_R(15) TF_R(26) TF_R(6)
  x0 += ks2; x1 += k0 + 5u;
#undef TF_R
  o0 = x0; o1 = x1;
}

// Relaxed agent-scope (cache-bypassing, L3-coherent) data exchange.
__device__ __forceinline__ void st_bypass(double* p, double v) {
  __hip_atomic_store(p, v, __ATOMIC_RELAXED, __HIP_MEMORY_SCOPE_AGENT);
}
__device__ __forceinline__ double ld_bypass(const double* p) {
  return __hip_atomic_load(p, __ATOMIC_RELAXED, __HIP_MEMORY_SCOPE_AGENT);
}

// 8-way group barrier with NO cache maintenance:
// per-thread vmcnt drain -> block sync -> relaxed flag store -> relaxed spin.
__device__ __forceinline__ void gbar8(unsigned* flags, int slot, unsigned target) {
  asm volatile("s_waitcnt vmcnt(0)" ::: "memory");
  __syncthreads();
  if (threadIdx.x == 0)
    __hip_atomic_store(&flags[slot], target, __ATOMIC_RELAXED,
                       __HIP_MEMORY_SCOPE_AGENT);
  if (threadIdx.x < 8) {
    int guard = 0;
    while (__hip_atomic_load(&flags[threadIdx.x], __ATOMIC_RELAXED,
                             __HIP_MEMORY_SCOPE_AGENT) < target) {
      if (++guard > 5000000) break;  // safety: never hang the bench
    }
  }
  asm volatile("" ::: "memory");
  __syncthreads();
}

extern "C" __global__ __launch_bounds__(NTHR)
void wavernn_groups(const float* __restrict__ cond, const float* __restrict__ h0,
                    const float* __restrict__ W_ih, const float* __restrict__ W_hh,
                    const float* __restrict__ b_ih, const float* __restrict__ b_hh,
                    const float* __restrict__ W_hid, const float* __restrict__ b_hid,
                    const float* __restrict__ W_out, const float* __restrict__ b_out,
                    const float* __restrict__ emb,
                    float* __restrict__ out, double* __restrict__ ws) {
  const int tid = threadIdx.x;
  const int blk = blockIdx.x;
  const int g = blk >> 3;   // batch element (group)
  const int j = blk & 7;    // slot in group; same slot -> same XCD across groups

  unsigned* flags = ((unsigned*)ws) + (size_t)g * 64;
  double* G   = ws + WS_DBL_BASE + (size_t)g * GRP_STRIDE;
  double* Hb0 = G;
  double* Hb1 = G + 512;
  double* PL  = G + 1024;   // 8 x 256 partial logits

  __shared__ __attribute__((aligned(32))) double s_x[Cn];
  __shared__ __attribute__((aligned(32))) double s_h[Gn];
  __shared__ __attribute__((aligned(32))) double s_hid[64];
  __shared__ double s_r[64], s_z[64], s_hn[64], s_in[64];
  __shared__ double s_part[64][4];
  __shared__ double s_red[NTHR];
  __shared__ int    s_idx[NTHR];

  // ---- init: H0 slice <- h0; x0 = cond[:,0,:] + emb[128] ----
  if (tid < 64) st_bypass(&Hb0[j * 64 + tid],
                          (double)h0[(size_t)g * Gn + j * 64 + tid]);
  if (tid < Cn) s_x[tid] = (double)cond[(size_t)g * Tn * Cn + tid]
                         + (double)emb[128 * Cn + tid];
  unsigned pc = 1;
  gbar8(flags, j, pc++);

  for (int t = 0; t < Tn; ++t) {
    double* hcur = (t & 1) ? Hb1 : Hb0;
    double* hnxt = (t & 1) ? Hb0 : Hb1;

    // ============ Phase A: gate dots + combine (own 64-g slice) ============
    s_h[tid] = ld_bypass(&hcur[tid]);
    s_h[tid + 256] = ld_bypass(&hcur[tid + 256]);
    __syncthreads();
    {
      const int part = tid >> 6, gl = tid & 63;
      const double4* x4 = (const double4*)s_x;
      const double4* h4 = (const double4*)s_h;
      if (part <= 1) {
        // r (part 0) / z (part 1): x.Wih + h.Whh + biases -> sigmoid
        const int row = part * 512 + j * 64 + gl;
        const float4* wi = (const float4*)(W_ih + (size_t)row * Cn);
        const float4* wh = (const float4*)(W_hh + (size_t)row * Gn);
        double a0 = 0., a1 = 0., a2 = 0., a3 = 0.;
#pragma unroll 8
        for (int k = 0; k < Cn / 4; ++k) {
          float4 w = wi[k]; double4 xv = x4[k];
          a0 = fma((double)w.x, xv.x, a0); a1 = fma((double)w.y, xv.y, a1);
          a2 = fma((double)w.z, xv.z, a2); a3 = fma((double)w.w, xv.w, a3);
        }
#pragma unroll 8
        for (int k = 0; k < Gn / 4; ++k) {
          float4 w = wh[k]; double4 hv = h4[k];
          a0 = fma((double)w.x, hv.x, a0); a1 = fma((double)w.y, hv.y, a1);
          a2 = fma((double)w.z, hv.z, a2); a3 = fma((double)w.w, hv.w, a3);
        }
        double pre = ((a0 + a1) + (a2 + a3)) + (double)b_ih[row] + (double)b_hh[row];
        double sig = 1.0 / (1.0 + exp(-pre));
        if (part == 0) s_r[gl] = sig; else s_z[gl] = sig;
      } else if (part == 2) {
        const int row = 1024 + j * 64 + gl;
        const float4* wh = (const float4*)(W_hh + (size_t)row * Gn);
        double a0 = 0., a1 = 0., a2 = 0., a3 = 0.;
#pragma unroll 8
        for (int k = 0; k < Gn / 4; ++k) {
          float4 w = wh[k]; double4 hv = h4[k];
          a0 = fma((double)w.x, hv.x, a0); a1 = fma((double)w.y, hv.y, a1);
          a2 = fma((double)w.z, hv.z, a2); a3 = fma((double)w.w, hv.w, a3);
        }
        s_hn[gl] = ((a0 + a1) + (a2 + a3)) + (double)b_hh[row];
      } else {
        const int row = 1024 + j * 64 + gl;
        const float4* wi = (const float4*)(W_ih + (size_t)row * Cn);
        double a0 = 0., a1 = 0., a2 = 0., a3 = 0.;
#pragma unroll 8
        for (int k = 0; k < Cn / 4; ++k) {
          float4 w = wi[k]; double4 xv = x4[k];
          a0 = fma((double)w.x, xv.x, a0); a1 = fma((double)w.y, xv.y, a1);
          a2 = fma((double)w.z, xv.z, a2); a3 = fma((double)w.w, xv.w, a3);
        }
        s_in[gl] = ((a0 + a1) + (a2 + a3)) + (double)b_ih[row];
      }
    }
    __syncthreads();
    if (tid < 64) {
      double r = s_r[tid], z = s_z[tid];
      double n = tanh(s_in[tid] + r * s_hn[tid]);
      double hv = (1.0 - z) * n + z * s_h[j * 64 + tid];
      st_bypass(&hnxt[j * 64 + tid], hv);
    }
    gbar8(flags, j, pc++);

    // ============ Phase B: hid slice + partial logits (all local) ==========
    // prefetch next cond early (independent of sampling)
    float cond_next = 0.f;
    if (t + 1 < Tn && tid < Cn)
      cond_next = cond[((size_t)g * Tn + (t + 1)) * Cn + tid];

    s_h[tid] = ld_bypass(&hnxt[tid]);
    s_h[tid + 256] = ld_bypass(&hnxt[tid + 256]);
    __syncthreads();
    if (t == Tn - 1 && j == 0) {
      out[OUT_HF + (size_t)g * Gn + tid] = (float)s_h[tid];
      out[OUT_HF + (size_t)g * Gn + tid + 256] = (float)s_h[tid + 256];
    }
    {
      // hid rows [64j,64j+64): row = tid>>2, k-quarter = tid&3 (128 k each)
      const int row = j * 64 + (tid >> 2);
      const int q = tid & 3;
      const float4* wr = (const float4*)(W_hid + (size_t)row * Gn + q * 128);
      const double4* hh = (const double4*)(s_h + q * 128);
      double a0 = 0., a1 = 0., a2 = 0., a3 = 0.;
#pragma unroll 8
      for (int k = 0; k < 32; ++k) {
        float4 w = wr[k]; double4 hv = hh[k];
        a0 = fma((double)w.x, hv.x, a0); a1 = fma((double)w.y, hv.y, a1);
        a2 = fma((double)w.z, hv.z, a2); a3 = fma((double)w.w, hv.w, a3);
      }
      s_part[tid >> 2][q] = (a0 + a1) + (a2 + a3);
    }
    __syncthreads();
    if (tid < 64) {
      double acc = (s_part[tid][0] + s_part[tid][1])
                 + (s_part[tid][2] + s_part[tid][3])
                 + (double)b_hid[j * 64 + tid];
      s_hid[tid] = acc > 0.0 ? acc : 0.0;
    }
    __syncthreads();
    {
      // partial logits over own k-slice for ALL 256 buckets
      const int v = tid;
      const float4* wr = (const float4*)(W_out + (size_t)v * Hn + j * 64);
      const double4* hh = (const double4*)s_hid;
      double a0 = 0., a1 = 0., a2 = 0., a3 = 0.;
#pragma unroll 8
      for (int k = 0; k < 16; ++k) {
        float4 w = wr[k]; double4 hv = hh[k];
        a0 = fma((double)w.x, hv.x, a0); a1 = fma((double)w.y, hv.y, a1);
        a2 = fma((double)w.z, hv.z, a2); a3 = fma((double)w.w, hv.w, a3);
      }
      st_bypass(&PL[j * 256 + v], (a0 + a1) + (a2 + a3));
    }
    gbar8(flags, j, pc++);

    // ============ Resolve: sum partials, gumbel, argmax (redundant) ========
    {
      const int v = tid;
      double l0 = ld_bypass(&PL[0 * 256 + v]);
      double l1 = ld_bypass(&PL[1 * 256 + v]);
      double l2 = ld_bypass(&PL[2 * 256 + v]);
      double l3 = ld_bypass(&PL[3 * 256 + v]);
      double l4 = ld_bypass(&PL[4 * 256 + v]);
      double l5 = ld_bypass(&PL[5 * 256 + v]);
      double l6 = ld_bypass(&PL[6 * 256 + v]);
      double l7 = ld_bypass(&PL[7 * 256 + v]);
      double logit = ((((((((l0 + l1) + l2) + l3) + l4) + l5) + l6) + l7))
                   + (double)b_out[v];
      if (j == 0)
        out[(size_t)g * Tn * Vn + (size_t)t * Vn + v] = (float)logit;

      // JAX partitionable threefry: keys[t]=tf((0,1),(0,t)); bits=o0^o1 of
      // tf(keys[t],(0, g*256+v))
      unsigned kt0, kt1, r0, r1;
      threefry2x32(0u, 1u, 0u, (unsigned)t, kt0, kt1);
      threefry2x32(kt0, kt1, 0u, (unsigned)(g * Vn + v), r0, r1);
      unsigned bits = r0 ^ r1;
      float uf = __uint_as_float((bits >> 9) | 0x3f800000u) - 1.0f;
      if (uf <= 0.f) uf = 1.17549435e-38f;  // np.finfo(float32).tiny
      double gum = -log(-log((double)uf));
      s_red[tid] = logit + gum;
      s_idx[tid] = v;
    }
    __syncthreads();
    for (int s2 = NTHR / 2; s2 > 0; s2 >>= 1) {
      if (tid < s2) {
        double ov = s_red[tid + s2]; int oi = s_idx[tid + s2];
        if (ov > s_red[tid] || (ov == s_red[tid] && oi < s_idx[tid])) {
          s_red[tid] = ov; s_idx[tid] = oi;
        }
      }
      __syncthreads();
    }
    const int samp = s_idx[0];
    if (tid == 0 && j == 0) out[OUT_SAMP + (size_t)g * Tn + t] = (float)samp;
    if (t + 1 < Tn && tid < Cn) {
      s_x[tid] = (double)cond_next + (double)emb[(size_t)samp * Cn + tid];
    }
    // s_x writes ordered before next phase-A reads by phase-A's __syncthreads.
  }
}

extern "C" void kernel_launch(void* const* d_in, const int* in_sizes, int n_in,
                              void* d_out, int out_size, void* d_ws, size_t ws_size,
                              hipStream_t stream) {
  const float* cond  = (const float*)d_in[0];
  const float* h0    = (const float*)d_in[1];
  const float* W_ih  = (const float*)d_in[2];
  const float* W_hh  = (const float*)d_in[3];
  const float* b_ih  = (const float*)d_in[4];
  const float* b_hh  = (const float*)d_in[5];
  const float* W_hid = (const float*)d_in[6];
  const float* b_hid = (const float*)d_in[7];
  const float* W_out = (const float*)d_in[8];
  const float* b_out = (const float*)d_in[9];
  const float* emb   = (const float*)d_in[10];

  // zero the flag region (ws is poisoned 0xAA before every call)
  hipMemsetAsync(d_ws, 0, 4096, stream);
  hipLaunchKernelGGL(wavernn_groups, dim3(NBLK), dim3(NTHR), 0, stream,
                     cond, h0, W_ih, W_hh, b_ih, b_hh, W_hid, b_hid,
                     W_out, b_out, emb, (float*)d_out, (double*)d_ws);
}

// Round 6
// 51333.722 us; speedup vs baseline: 4.0930x; 1.0815x over previous
//
#include <hip/hip_runtime.h>
#include <stdint.h>
#include <math.h>

#define NBLK 128
#define NTHR 256
#define Bn 16
#define Tn 2000
#define Cn 128
#define Gn 512
#define Hn 512
#define Vn 256

// ws: first 4096 B = flags (16 groups x 64 u32; group g at g*256 B, 8 used).
// Then doubles per group (stride 3072): H0[0,512) H1[512,1024) PL[1024,3072)
#define WS_DBL_BASE 512
#define GRP_STRIDE  3072

#define OUT_SAMP ((size_t)Bn*Tn*Vn)          // 8,192,000
#define OUT_HF   (OUT_SAMP + (size_t)Bn*Tn)  // 8,224,000

typedef __attribute__((ext_vector_type(2))) double d2_t;

__device__ __forceinline__ unsigned rotl32(unsigned v, int n) {
  return (v << n) | (v >> (32 - n));
}

// JAX threefry2x32, 20 rounds, exact.
__device__ __forceinline__ void threefry2x32(unsigned k0, unsigned k1,
                                             unsigned c0, unsigned c1,
                                             unsigned& o0, unsigned& o1) {
  unsigned ks2 = k0 ^ k1 ^ 0x1BD11BDAu;
  unsigned x0 = c0 + k0;
  unsigned x1 = c1 + k1;
#define TF_R(r) { x0 += x1; x1 = rotl32(x1, r); x1 ^= x0; }
  TF_R(13) TF_R(15) TF_R(26) TF_R(6)
  x0 += k1;  x1 += ks2 + 1u;
  TF_R(17) TF_R(29) TF_R(16) TF_R(24)
  x0 += ks2; x1 += k0 + 2u;
  TF_R(13) TF_R(15) TF_R(26) TF_R(6)
  x0 += k0;  x1 += k1 + 3u;
  TF_R(17) TF_R(29) TF_R(16) TF_R(24)
  x0 += k1;  x1 += ks2 + 4u;
  TF_R(13) TF_R(15) TF_R(26) TF_R(6)
  x0 += ks2; x1 += k0 + 5u;
#undef TF_R
  o0 = x0; o1 = x1;
}

// ---- cross-block traffic: NORMAL-encoding sc0 sc1 ops (L3-coherent fast
// path; the __hip_atomic_* versions take the slow TCC atomic path). ----
__device__ __forceinline__ void st_d(double* p, double v) {
  asm volatile("global_store_dwordx2 %0, %1, off sc0 sc1"
               :: "v"(p), "v"(v) : "memory");
}
__device__ __forceinline__ d2_t ld_d2(const double* p) {
  d2_t r;
  asm volatile("global_load_dwordx4 %0, %1, off sc0 sc1\n\t"
               "s_waitcnt vmcnt(0)" : "=v"(r) : "v"(p));
  return r;
}
__device__ __forceinline__ void ld8(const double* pl, int v, double* o) {
  const double* a0 = pl + v;
  const double* a1 = pl + 512 + v;
  const double* a2 = pl + 1024 + v;
  const double* a3 = pl + 1536 + v;
  double o0, o1, o2, o3, o4, o5, o6, o7;
  asm volatile(
    "global_load_dwordx2 %[r0], %[p0], off sc0 sc1\n\t"
    "global_load_dwordx2 %[r1], %[p0], off offset:2048 sc0 sc1\n\t"
    "global_load_dwordx2 %[r2], %[p1], off sc0 sc1\n\t"
    "global_load_dwordx2 %[r3], %[p1], off offset:2048 sc0 sc1\n\t"
    "global_load_dwordx2 %[r4], %[p2], off sc0 sc1\n\t"
    "global_load_dwordx2 %[r5], %[p2], off offset:2048 sc0 sc1\n\t"
    "global_load_dwordx2 %[r6], %[p3], off sc0 sc1\n\t"
    "global_load_dwordx2 %[r7], %[p3], off offset:2048 sc0 sc1\n\t"
    "s_waitcnt vmcnt(0)"
    : [r0]"=v"(o0), [r1]"=v"(o1), [r2]"=v"(o2), [r3]"=v"(o3),
      [r4]"=v"(o4), [r5]"=v"(o5), [r6]"=v"(o6), [r7]"=v"(o7)
    : [p0]"v"(a0), [p1]"v"(a1), [p2]"v"(a2), [p3]"v"(a3));
  o[0]=o0; o[1]=o1; o[2]=o2; o[3]=o3; o[4]=o4; o[5]=o5; o[6]=o6; o[7]=o7;
}
__device__ __forceinline__ unsigned ld_u(const unsigned* p) {
  unsigned r;
  asm volatile("global_load_dword %0, %1, off sc0 sc1\n\t"
               "s_waitcnt vmcnt(0)" : "=v"(r) : "v"(p) : "memory");
  return r;
}
__device__ __forceinline__ void st_u(unsigned* p, unsigned v) {
  asm volatile("global_store_dword %0, %1, off sc0 sc1"
               :: "v"(p), "v"(v) : "memory");
}

// split 8-way group barrier: arrive (drain stores + flag), then wait (spin).
__device__ __forceinline__ void gar(unsigned* flags, int slot, unsigned target) {
  asm volatile("s_waitcnt vmcnt(0)" ::: "memory");
  __syncthreads();
  if (threadIdx.x == 0) st_u(&flags[slot], target);
}
__device__ __forceinline__ void gwt(unsigned* flags, unsigned target) {
  if (threadIdx.x < 8) {
    int guard = 0;
    while (ld_u(&flags[threadIdx.x]) < target) {
      if (++guard > 5000000) break;  // safety: never hang the bench
    }
  }
  asm volatile("" ::: "memory");
  __syncthreads();
}

extern "C" __global__ __launch_bounds__(NTHR)
void wavernn_groups(const float* __restrict__ cond, const float* __restrict__ h0,
                    const float* __restrict__ W_ih, const float* __restrict__ W_hh,
                    const float* __restrict__ b_ih, const float* __restrict__ b_hh,
                    const float* __restrict__ W_hid, const float* __restrict__ b_hid,
                    const float* __restrict__ W_out, const float* __restrict__ b_out,
                    const float* __restrict__ emb,
                    float* __restrict__ out, double* __restrict__ ws) {
  const int tid = threadIdx.x;
  const int blk = blockIdx.x;
  const int g = blk >> 3;   // batch element (group)
  const int j = blk & 7;    // slot; slot-major => weight slice j is XCD-local

  unsigned* flags = ((unsigned*)ws) + (size_t)g * 64;
  double* G   = ws + WS_DBL_BASE + (size_t)g * GRP_STRIDE;
  double* Hb0 = G;
  double* Hb1 = G + 512;
  double* PL  = G + 1024;   // 8 x 256 partial logits

  __shared__ __attribute__((aligned(32))) double s_x[Cn];
  __shared__ __attribute__((aligned(32))) double s_h[Gn];
  __shared__ __attribute__((aligned(32))) double s_hid[64];
  __shared__ double s_r[64], s_z[64], s_hn[64], s_in[64];
  __shared__ double s_part[4][64];
  __shared__ double s_pv[4];
  __shared__ int    s_pi[4];

  // ---- init: H0 slice <- h0; x0 = cond[:,0,:] + emb[128] ----
  if (tid < 64) st_d(&Hb0[j * 64 + tid],
                     (double)h0[(size_t)g * Gn + j * 64 + tid]);
  if (tid < Cn) s_x[tid] = (double)cond[(size_t)g * Tn * Cn + tid]
                         + (double)emb[128 * Cn + tid];
  unsigned pc = 1;
  gar(flags, j, pc); gwt(flags, pc); pc++;

  for (int t = 0; t < Tn; ++t) {
    double* hcur = (t & 1) ? Hb1 : Hb0;
    double* hnxt = (t & 1) ? Hb0 : Hb1;

    // ============ Phase A: gate dots + combine (own 64-g slice) ============
    ((d2_t*)s_h)[tid] = ld_d2(hcur + 2 * tid);
    __syncthreads();
    {
      const int part = tid >> 6, gl = tid & 63;
      const double4* x4 = (const double4*)s_x;
      const double4* h4 = (const double4*)s_h;
      if (part <= 1) {
        const int row = part * 512 + j * 64 + gl;
        const float4* wi = (const float4*)(W_ih + (size_t)row * Cn);
        const float4* wh = (const float4*)(W_hh + (size_t)row * Gn);
        double a0 = 0., a1 = 0., a2 = 0., a3 = 0.;
#pragma unroll 8
        for (int k = 0; k < Cn / 4; ++k) {
          float4 w = wi[k]; double4 xv = x4[k];
          a0 = fma((double)w.x, xv.x, a0); a1 = fma((double)w.y, xv.y, a1);
          a2 = fma((double)w.z, xv.z, a2); a3 = fma((double)w.w, xv.w, a3);
        }
#pragma unroll 8
        for (int k = 0; k < Gn / 4; ++k) {
          float4 w = wh[k]; double4 hv = h4[k];
          a0 = fma((double)w.x, hv.x, a0); a1 = fma((double)w.y, hv.y, a1);
          a2 = fma((double)w.z, hv.z, a2); a3 = fma((double)w.w, hv.w, a3);
        }
        double pre = ((a0 + a1) + (a2 + a3)) + (double)b_ih[row] + (double)b_hh[row];
        double sig = 1.0 / (1.0 + exp(-pre));
        if (part == 0) s_r[gl] = sig; else s_z[gl] = sig;
      } else if (part == 2) {
        const int row = 1024 + j * 64 + gl;
        const float4* wh = (const float4*)(W_hh + (size_t)row * Gn);
        double a0 = 0., a1 = 0., a2 = 0., a3 = 0.;
#pragma unroll 8
        for (int k = 0; k < Gn / 4; ++k) {
          float4 w = wh[k]; double4 hv = h4[k];
          a0 = fma((double)w.x, hv.x, a0); a1 = fma((double)w.y, hv.y, a1);
          a2 = fma((double)w.z, hv.z, a2); a3 = fma((double)w.w, hv.w, a3);
        }
        s_hn[gl] = ((a0 + a1) + (a2 + a3)) + (double)b_hh[row];
      } else {
        const int row = 1024 + j * 64 + gl;
        const float4* wi = (const float4*)(W_ih + (size_t)row * Cn);
        double a0 = 0., a1 = 0., a2 = 0., a3 = 0.;
#pragma unroll 8
        for (int k = 0; k < Cn / 4; ++k) {
          float4 w = wi[k]; double4 xv = x4[k];
          a0 = fma((double)w.x, xv.x, a0); a1 = fma((double)w.y, xv.y, a1);
          a2 = fma((double)w.z, xv.z, a2); a3 = fma((double)w.w, xv.w, a3);
        }
        s_in[gl] = ((a0 + a1) + (a2 + a3)) + (double)b_ih[row];
      }
    }
    __syncthreads();
    if (tid < 64) {
      double r = s_r[tid], z = s_z[tid];
      double n = tanh(s_in[tid] + r * s_hn[tid]);
      double hv = (1.0 - z) * n + z * s_h[j * 64 + tid];
      st_d(&hnxt[j * 64 + tid], hv);
    }
    gar(flags, j, pc);
    // --- overlapped under barrier A: cond prefetch + step key ---
    float cond_next = 0.f;
    if (t + 1 < Tn && tid < Cn)
      cond_next = cond[((size_t)g * Tn + (t + 1)) * Cn + tid];
    unsigned kt0, kt1;
    threefry2x32(0u, 1u, 0u, (unsigned)t, kt0, kt1);
    gwt(flags, pc); pc++;

    // ============ Phase B: hid slice + partial logits (all local) ==========
    ((d2_t*)s_h)[tid] = ld_d2(hnxt + 2 * tid);
    __syncthreads();
    if (t == Tn - 1 && j == 0) {
      out[OUT_HF + (size_t)g * Gn + tid] = (float)s_h[tid];
      out[OUT_HF + (size_t)g * Gn + tid + 256] = (float)s_h[tid + 256];
    }
    {
      // hid rows [64j,64j+64): row = tid&63, k-quarter q = tid>>6 (wave-
      // uniform -> broadcast LDS reads, no bank conflicts)
      const int row = j * 64 + (tid & 63);
      const int q = tid >> 6;
      const float4* wr = (const float4*)(W_hid + (size_t)row * Gn + q * 128);
      const double4* hh = (const double4*)(s_h + q * 128);
      double a0 = 0., a1 = 0., a2 = 0., a3 = 0.;
#pragma unroll 8
      for (int k = 0; k < 32; ++k) {
        float4 w = wr[k]; double4 hv = hh[k];
        a0 = fma((double)w.x, hv.x, a0); a1 = fma((double)w.y, hv.y, a1);
        a2 = fma((double)w.z, hv.z, a2); a3 = fma((double)w.w, hv.w, a3);
      }
      s_part[q][tid & 63] = (a0 + a1) + (a2 + a3);
    }
    __syncthreads();
    if (tid < 64) {
      double acc = (s_part[0][tid] + s_part[1][tid])
                 + (s_part[2][tid] + s_part[3][tid])
                 + (double)b_hid[j * 64 + tid];
      s_hid[tid] = acc > 0.0 ? acc : 0.0;
    }
    __syncthreads();
    {
      // partial logits over own 64-k slice for ALL 256 buckets
      const int v = tid;
      const float4* wr = (const float4*)(W_out + (size_t)v * Hn + j * 64);
      const double4* hh = (const double4*)s_hid;
      double a0 = 0., a1 = 0., a2 = 0., a3 = 0.;
#pragma unroll 8
      for (int k = 0; k < 16; ++k) {
        float4 w = wr[k]; double4 hv = hh[k];
        a0 = fma((double)w.x, hv.x, a0); a1 = fma((double)w.y, hv.y, a1);
        a2 = fma((double)w.z, hv.z, a2); a3 = fma((double)w.w, hv.w, a3);
      }
      st_d(&PL[j * 256 + v], (a0 + a1) + (a2 + a3));
    }
    gar(flags, j, pc);
    // --- overlapped under barrier B: exact JAX gumbel for own v=tid ---
    double gum;
    {
      unsigned r0, r1;
      threefry2x32(kt0, kt1, 0u, (unsigned)(g * Vn + tid), r0, r1);
      unsigned bits = r0 ^ r1;
      float uf = __uint_as_float((bits >> 9) | 0x3f800000u) - 1.0f;
      if (uf <= 0.f) uf = 1.17549435e-38f;  // np.finfo(float32).tiny
      gum = -log(-log((double)uf));
    }
    gwt(flags, pc); pc++;

    // ============ Resolve: sum partials, argmax (redundant per block) ======
    int samp;
    {
      const int v = tid;
      double l[8];
      ld8(PL, v, l);
      double logit = ((((((((l[0] + l[1]) + l[2]) + l[3]) + l[4]) + l[5])
                       + l[6]) + l[7])) + (double)b_out[v];
      if (j == 0)
        out[(size_t)g * Tn * Vn + (size_t)t * Vn + v] = (float)logit;

      double bv = logit + gum;
      int bi = v;
#pragma unroll
      for (int off = 1; off < 64; off <<= 1) {
        double ov = __shfl_xor(bv, off, 64);
        int oi = __shfl_xor(bi, off, 64);
        if (ov > bv || (ov == bv && oi < bi)) { bv = ov; bi = oi; }
      }
      if ((tid & 63) == 0) { s_pv[tid >> 6] = bv; s_pi[tid >> 6] = bi; }
      __syncthreads();
      double fv = s_pv[0]; int fi = s_pi[0];
#pragma unroll
      for (int w = 1; w < 4; ++w) {
        double ov = s_pv[w]; int oi = s_pi[w];
        if (ov > fv || (ov == fv && oi < fi)) { fv = ov; fi = oi; }
      }
      samp = fi;
    }
    if (tid == 0 && j == 0) out[OUT_SAMP + (size_t)g * Tn + t] = (float)samp;
    if (t + 1 < Tn && tid < Cn) {
      s_x[tid] = (double)cond_next + (double)emb[(size_t)samp * Cn + tid];
    }
    // s_x/LDS reuse ordered by next phase-A __syncthreads.
  }
}

extern "C" void kernel_launch(void* const* d_in, const int* in_sizes, int n_in,
                              void* d_out, int out_size, void* d_ws, size_t ws_size,
                              hipStream_t stream) {
  const float* cond  = (const float*)d_in[0];
  const float* h0    = (const float*)d_in[1];
  const float* W_ih  = (const float*)d_in[2];
  const float* W_hh  = (const float*)d_in[3];
  const float* b_ih  = (const float*)d_in[4];
  const float* b_hh  = (const float*)d_in[5];
  const float* W_hid = (const float*)d_in[6];
  const float* b_hid = (const float*)d_in[7];
  const float* W_out = (const float*)d_in[8];
  const float* b_out = (const float*)d_in[9];
  const float* emb   = (const float*)d_in[10];

  // zero the flag region (ws is poisoned 0xAA before every call)
  hipMemsetAsync(d_ws, 0, 4096, stream);
  hipLaunchKernelGGL(wavernn_groups, dim3(NBLK), dim3(NTHR), 0, stream,
                     cond, h0, W_ih, W_hh, b_ih, b_hh, W_hid, b_hid,
                     W_out, b_out, emb, (float*)d_out, (double*)d_ws);
}

// Round 7
// 48876.321 us; speedup vs baseline: 4.2987x; 1.0503x over previous
//
#include <hip/hip_runtime.h>
#include <stdint.h>
#include <math.h>

#define NBLK 128
#define NTHR 256
#define Bn 16
#define Tn 2000
#define Cn 128
#define Gn 512
#define Hn 512
#define Vn 256

// ws: first 4096 B = flags (16 groups x 64 u32; group g at g*256 B, 8 used).
// Then doubles per group (stride 3072): H0[0,512) H1[512,1024) PL[1024,3072)
#define WS_DBL_BASE 512
#define GRP_STRIDE  3072

#define OUT_SAMP ((size_t)Bn*Tn*Vn)          // 8,192,000
#define OUT_HF   (OUT_SAMP + (size_t)Bn*Tn)  // 8,224,000

typedef __attribute__((ext_vector_type(2))) double d2_t;

__device__ __forceinline__ unsigned rotl32(unsigned v, int n) {
  return (v << n) | (v >> (32 - n));
}

// JAX threefry2x32, 20 rounds, exact.
__device__ __forceinline__ void threefry2x32(unsigned k0, unsigned k1,
                                             unsigned c0, unsigned c1,
                                             unsigned& o0, unsigned& o1) {
  unsigned ks2 = k0 ^ k1 ^ 0x1BD11BDAu;
  unsigned x0 = c0 + k0;
  unsigned x1 = c1 + k1;
#define TF_R(r) { x0 += x1; x1 = rotl32(x1, r); x1 ^= x0; }
  TF_R(13) TF_R(15) TF_R(26) TF_R(6)
  x0 += k1;  x1 += ks2 + 1u;
  TF_R(17) TF_R(29) TF_R(16) TF_R(24)
  x0 += ks2; x1 += k0 + 2u;
  TF_R(13) TF_R(15) TF_R(26) TF_R(6)
  x0 += k0;  x1 += k1 + 3u;
  TF_R(17) TF_R(29) TF_R(16) TF_R(24)
  x0 += k1;  x1 += ks2 + 4u;
  TF_R(13) TF_R(15) TF_R(26) TF_R(6)
  x0 += ks2; x1 += k0 + 5u;
#undef TF_R
  o0 = x0; o1 = x1;
}

// exact JAX partitionable gumbel for step key (kt0,kt1), flat index f
__device__ __forceinline__ double jax_gumbel(unsigned kt0, unsigned kt1,
                                             unsigned f) {
  unsigned r0, r1;
  threefry2x32(kt0, kt1, 0u, f, r0, r1);
  unsigned bits = r0 ^ r1;
  float uf = __uint_as_float((bits >> 9) | 0x3f800000u) - 1.0f;
  if (uf <= 0.f) uf = 1.17549435e-38f;  // np.finfo(float32).tiny
  return -log(-log((double)uf));
}

// ---- cross-block traffic: NORMAL-encoding sc0 sc1 ops (L3-coherent). ----
__device__ __forceinline__ void st_d(double* p, double v) {
  asm volatile("global_store_dwordx2 %0, %1, off sc0 sc1"
               :: "v"(p), "v"(v) : "memory");
}
__device__ __forceinline__ d2_t ld_d2(const double* p) {
  d2_t r;
  asm volatile("global_load_dwordx4 %0, %1, off sc0 sc1\n\t"
               "s_waitcnt vmcnt(0)" : "=v"(r) : "v"(p));
  return r;
}
__device__ __forceinline__ void ld8(const double* pl, int v, double* o) {
  const double* a0 = pl + v;
  const double* a1 = pl + 512 + v;
  const double* a2 = pl + 1024 + v;
  const double* a3 = pl + 1536 + v;
  double o0, o1, o2, o3, o4, o5, o6, o7;
  asm volatile(
    "global_load_dwordx2 %[r0], %[p0], off sc0 sc1\n\t"
    "global_load_dwordx2 %[r1], %[p0], off offset:2048 sc0 sc1\n\t"
    "global_load_dwordx2 %[r2], %[p1], off sc0 sc1\n\t"
    "global_load_dwordx2 %[r3], %[p1], off offset:2048 sc0 sc1\n\t"
    "global_load_dwordx2 %[r4], %[p2], off sc0 sc1\n\t"
    "global_load_dwordx2 %[r5], %[p2], off offset:2048 sc0 sc1\n\t"
    "global_load_dwordx2 %[r6], %[p3], off sc0 sc1\n\t"
    "global_load_dwordx2 %[r7], %[p3], off offset:2048 sc0 sc1\n\t"
    "s_waitcnt vmcnt(0)"
    : [r0]"=v"(o0), [r1]"=v"(o1), [r2]"=v"(o2), [r3]"=v"(o3),
      [r4]"=v"(o4), [r5]"=v"(o5), [r6]"=v"(o6), [r7]"=v"(o7)
    : [p0]"v"(a0), [p1]"v"(a1), [p2]"v"(a2), [p3]"v"(a3));
  o[0]=o0; o[1]=o1; o[2]=o2; o[3]=o3; o[4]=o4; o[5]=o5; o[6]=o6; o[7]=o7;
}
__device__ __forceinline__ unsigned ld_u(const unsigned* p) {
  unsigned r;
  asm volatile("global_load_dword %0, %1, off sc0 sc1\n\t"
               "s_waitcnt vmcnt(0)" : "=v"(r) : "v"(p) : "memory");
  return r;
}
__device__ __forceinline__ void st_u(unsigned* p, unsigned v) {
  asm volatile("global_store_dword %0, %1, off sc0 sc1"
               :: "v"(p), "v"(v) : "memory");
}

// split 8-way group barrier: arrive (drain stores + flag), then wait (spin).
__device__ __forceinline__ void gar(unsigned* flags, int slot, unsigned target) {
  asm volatile("s_waitcnt vmcnt(0)" ::: "memory");
  __syncthreads();
  if (threadIdx.x == 0) st_u(&flags[slot], target);
}
__device__ __forceinline__ void gwt(unsigned* flags, unsigned target) {
  if (threadIdx.x < 8) {
    int guard = 0;
    while (ld_u(&flags[threadIdx.x]) < target) {
      if (++guard > 5000000) break;  // safety: never hang the bench
    }
  }
  asm volatile("" ::: "memory");
  __syncthreads();
}

extern "C" __global__ __launch_bounds__(NTHR)
void wavernn_pipe(const float* __restrict__ cond, const float* __restrict__ h0,
                  const float* __restrict__ W_ih, const float* __restrict__ W_hh,
                  const float* __restrict__ b_ih, const float* __restrict__ b_hh,
                  const float* __restrict__ W_hid, const float* __restrict__ b_hid,
                  const float* __restrict__ W_out, const float* __restrict__ b_out,
                  const float* __restrict__ emb,
                  float* __restrict__ out, double* __restrict__ ws) {
  const int tid = threadIdx.x;
  const int blk = blockIdx.x;
  const int g = blk >> 3;   // batch element (group)
  const int j = blk & 7;    // slot; slot-major => weight slice j is XCD-local
  const int lane = tid & 63, wv = tid >> 6;

  unsigned* flags = ((unsigned*)ws) + (size_t)g * 64;
  double* G   = ws + WS_DBL_BASE + (size_t)g * GRP_STRIDE;
  double* Hb0 = G;
  double* Hb1 = G + 512;
  double* PL  = G + 1024;   // 8 x 256 partial logits

  __shared__ __attribute__((aligned(32))) double s_x[Cn];
  __shared__ __attribute__((aligned(32))) double s_h[Gn];
  __shared__ __attribute__((aligned(32))) double s_hid[64];
  __shared__ double s_hn[64], s_in[64], s_z[64];
  __shared__ double s_part[4][64];
  __shared__ double s_gum[256];
  __shared__ float  s_cond[Cn];
  __shared__ double s_pv[4];
  __shared__ int    s_pi[4];

  // ---- init: H0 slice <- h0; x0 = cond[:,0,:] + emb[128] ----
  if (tid < 64) st_d(&Hb0[j * 64 + tid],
                     (double)h0[(size_t)g * Gn + j * 64 + tid]);
  if (tid < Cn) s_x[tid] = (double)cond[(size_t)g * Tn * Cn + tid]
                         + (double)emb[128 * Cn + tid];
  gar(flags, j, 1u); gwt(flags, 1u);
  ((d2_t*)s_h)[tid] = ld_d2(Hb0 + 2 * tid);   // s_h = h_0
  __syncthreads();

  for (int t = 0; t < Tn; ++t) {
    double* hnxt = (t & 1) ? Hb0 : Hb1;       // buffer for h_{t+1}

    // ===== WINDOW (overlaps in-flight PL_{t-1} round trip) =====
    // h-dots over s_h = h_t. NEW ORDER: H-sum kept separate from X-sum.
    double ha0 = 0., ha1 = 0., ha2 = 0., ha3 = 0.;
    if (wv <= 2) {
      const int row = wv * 512 + j * 64 + lane;   // r(0) z(1) hn(2) rows
      const float4* wh = (const float4*)(W_hh + (size_t)row * Gn);
      const double4* h4 = (const double4*)s_h;
#pragma unroll 8
      for (int k = 0; k < Gn / 4; ++k) {
        float4 w = wh[k]; double4 hv = h4[k];
        ha0 = fma((double)w.x, hv.x, ha0); ha1 = fma((double)w.y, hv.y, ha1);
        ha2 = fma((double)w.z, hv.z, ha2); ha3 = fma((double)w.w, hv.w, ha3);
      }
      if (wv == 2)
        s_hn[lane] = ((ha0 + ha1) + (ha2 + ha3)) + (double)b_hh[row];
    } else {
      // wave 3: stage cond[:,t,:] ; gumbel for step t-1 (consumed at resolve)
      const int c0 = 2 * lane;
      s_cond[c0]     = cond[((size_t)g * Tn + t) * Cn + c0];
      s_cond[c0 + 1] = cond[((size_t)g * Tn + t) * Cn + c0 + 1];
      if (t > 0) {
        unsigned kt0, kt1;
        threefry2x32(0u, 1u, 0u, (unsigned)(t - 1), kt0, kt1);
#pragma unroll
        for (int i = 0; i < 4; ++i) {
          int v = 4 * lane + i;
          s_gum[v] = jax_gumbel(kt0, kt1, (unsigned)(g * Vn + v));
        }
      }
    }

    // ===== PL wait + resolve of step t-1 =====
    if (t > 0) {
      gwt(flags, (unsigned)(2 * t + 1));   // PL_{t-1} ready (gar'd 2(t-1)+3)
      const int v = tid;
      double l[8];
      ld8(PL, v, l);
      double logit = ((((((((l[0] + l[1]) + l[2]) + l[3]) + l[4]) + l[5])
                       + l[6]) + l[7])) + (double)b_out[v];
      if (j == 0)
        out[(size_t)g * Tn * Vn + (size_t)(t - 1) * Vn + v] = (float)logit;
      double bv = logit + s_gum[v];
      int bi = v;
#pragma unroll
      for (int off = 1; off < 64; off <<= 1) {
        double ov = __shfl_xor(bv, off, 64);
        int oi = __shfl_xor(bi, off, 64);
        if (ov > bv || (ov == bv && oi < bi)) { bv = ov; bi = oi; }
      }
      if (lane == 0) { s_pv[wv] = bv; s_pi[wv] = bi; }
      __syncthreads();
      double fv = s_pv[0]; int fi = s_pi[0];
#pragma unroll
      for (int w = 1; w < 4; ++w) {
        double ov = s_pv[w]; int oi = s_pi[w];
        if (ov > fv || (ov == fv && oi < fi)) { fv = ov; fi = oi; }
      }
      const int samp = fi;
      if (tid == 0 && j == 0)
        out[OUT_SAMP + (size_t)g * Tn + (t - 1)] = (float)samp;
      if (tid < Cn)
        s_x[tid] = (double)s_cond[tid] + (double)emb[(size_t)samp * Cn + tid];
      __syncthreads();
    } else {
      __syncthreads();  // order window LDS writes vs x-phase reads
    }

    // ===== x-phase: x-dots + sigmoids =====
    double r_reg = 0.;
    if (wv <= 1) {
      const int row = wv * 512 + j * 64 + lane;
      const float4* wi = (const float4*)(W_ih + (size_t)row * Cn);
      const double4* x4 = (const double4*)s_x;
      double xa0 = 0., xa1 = 0., xa2 = 0., xa3 = 0.;
#pragma unroll 8
      for (int k = 0; k < Cn / 4; ++k) {
        float4 w = wi[k]; double4 xv = x4[k];
        xa0 = fma((double)w.x, xv.x, xa0); xa1 = fma((double)w.y, xv.y, xa1);
        xa2 = fma((double)w.z, xv.z, xa2); xa3 = fma((double)w.w, xv.w, xa3);
      }
      double gi = ((xa0 + xa1) + (xa2 + xa3)) + (double)b_ih[row];
      double gh = ((ha0 + ha1) + (ha2 + ha3)) + (double)b_hh[row];
      double pre = gi + gh;
      double sig = 1.0 / (1.0 + exp(-pre));
      if (wv == 0) r_reg = sig; else s_z[lane] = sig;
    } else if (wv == 3) {
      const int row = 1024 + j * 64 + lane;
      const float4* wi = (const float4*)(W_ih + (size_t)row * Cn);
      const double4* x4 = (const double4*)s_x;
      double a0 = 0., a1 = 0., a2 = 0., a3 = 0.;
#pragma unroll 8
      for (int k = 0; k < Cn / 4; ++k) {
        float4 w = wi[k]; double4 xv = x4[k];
        a0 = fma((double)w.x, xv.x, a0); a1 = fma((double)w.y, xv.y, a1);
        a2 = fma((double)w.z, xv.z, a2); a3 = fma((double)w.w, xv.w, a3);
      }
      s_in[lane] = ((a0 + a1) + (a2 + a3)) + (double)b_ih[row];
    }
    __syncthreads();

    // ===== combine (wave 0) -> h_{t+1} slice =====
    if (wv == 0) {
      double z = s_z[lane];
      double n = tanh(s_in[lane] + r_reg * s_hn[lane]);
      double hv = (1.0 - z) * n + z * s_h[j * 64 + lane];
      st_d(&hnxt[j * 64 + lane], hv);
    }
    gar(flags, j, (unsigned)(2 * t + 2));
    gwt(flags, (unsigned)(2 * t + 2));
    ((d2_t*)s_h)[tid] = ld_d2(hnxt + 2 * tid);   // s_h = h_{t+1}
    __syncthreads();
    if (t == Tn - 1 && j == 0) {
      out[OUT_HF + (size_t)g * Gn + tid] = (float)s_h[tid];
      out[OUT_HF + (size_t)g * Gn + tid + 256] = (float)s_h[tid + 256];
    }

    // ===== B: hid slice + partial logits =====
    {
      const int row = j * 64 + lane;          // q = wv (wave-uniform)
      const float4* wr = (const float4*)(W_hid + (size_t)row * Gn + wv * 128);
      const double4* hh = (const double4*)(s_h + wv * 128);
      double a0 = 0., a1 = 0., a2 = 0., a3 = 0.;
#pragma unroll 8
      for (int k = 0; k < 32; ++k) {
        float4 w = wr[k]; double4 hv = hh[k];
        a0 = fma((double)w.x, hv.x, a0); a1 = fma((double)w.y, hv.y, a1);
        a2 = fma((double)w.z, hv.z, a2); a3 = fma((double)w.w, hv.w, a3);
      }
      s_part[wv][lane] = (a0 + a1) + (a2 + a3);
    }
    __syncthreads();
    if (tid < 64) {
      double acc = (s_part[0][tid] + s_part[1][tid])
                 + (s_part[2][tid] + s_part[3][tid])
                 + (double)b_hid[j * 64 + tid];
      s_hid[tid] = acc > 0.0 ? acc : 0.0;
    }
    __syncthreads();
    {
      const int v = tid;
      const float4* wr = (const float4*)(W_out + (size_t)v * Hn + j * 64);
      const double4* hh = (const double4*)s_hid;
      double a0 = 0., a1 = 0., a2 = 0., a3 = 0.;
#pragma unroll 8
      for (int k = 0; k < 16; ++k) {
        float4 w = wr[k]; double4 hv = hh[k];
        a0 = fma((double)w.x, hv.x, a0); a1 = fma((double)w.y, hv.y, a1);
        a2 = fma((double)w.z, hv.z, a2); a3 = fma((double)w.w, hv.w, a3);
      }
      st_d(&PL[j * 256 + v], (a0 + a1) + (a2 + a3));
    }
    gar(flags, j, (unsigned)(2 * t + 3));
  }

  // ===== final resolve: step Tn-1 =====
  gwt(flags, (unsigned)(2 * Tn + 1));
  {
    const int v = tid;
    double l[8];
    ld8(PL, v, l);
    double logit = ((((((((l[0] + l[1]) + l[2]) + l[3]) + l[4]) + l[5])
                     + l[6]) + l[7])) + (double)b_out[v];
    if (j == 0)
      out[(size_t)g * Tn * Vn + (size_t)(Tn - 1) * Vn + v] = (float)logit;
    unsigned kt0, kt1;
    threefry2x32(0u, 1u, 0u, (unsigned)(Tn - 1), kt0, kt1);
    double gum = jax_gumbel(kt0, kt1, (unsigned)(g * Vn + v));
    double bv = logit + gum;
    int bi = v;
#pragma unroll
    for (int off = 1; off < 64; off <<= 1) {
      double ov = __shfl_xor(bv, off, 64);
      int oi = __shfl_xor(bi, off, 64);
      if (ov > bv || (ov == bv && oi < bi)) { bv = ov; bi = oi; }
    }
    if (lane == 0) { s_pv[wv] = bv; s_pi[wv] = bi; }
    __syncthreads();
    double fv = s_pv[0]; int fi = s_pi[0];
#pragma unroll
    for (int w = 1; w < 4; ++w) {
      double ov = s_pv[w]; int oi = s_pi[w];
      if (ov > fv || (ov == fv && oi < fi)) { fv = ov; fi = oi; }
    }
    if (tid == 0 && j == 0)
      out[OUT_SAMP + (size_t)g * Tn + (Tn - 1)] = (float)fi;
  }
}

extern "C" void kernel_launch(void* const* d_in, const int* in_sizes, int n_in,
                              void* d_out, int out_size, void* d_ws, size_t ws_size,
                              hipStream_t stream) {
  const float* cond  = (const float*)d_in[0];
  const float* h0    = (const float*)d_in[1];
  const float* W_ih  = (const float*)d_in[2];
  const float* W_hh  = (const float*)d_in[3];
  const float* b_ih  = (const float*)d_in[4];
  const float* b_hh  = (const float*)d_in[5];
  const float* W_hid = (const float*)d_in[6];
  const float* b_hid = (const float*)d_in[7];
  const float* W_out = (const float*)d_in[8];
  const float* b_out = (const float*)d_in[9];
  const float* emb   = (const float*)d_in[10];

  // zero the flag region (ws is poisoned 0xAA before every call)
  hipMemsetAsync(d_ws, 0, 4096, stream);
  hipLaunchKernelGGL(wavernn_pipe, dim3(NBLK), dim3(NTHR), 0, stream,
                     cond, h0, W_ih, W_hh, b_ih, b_hh, W_hid, b_hid,
                     W_out, b_out, emb, (float*)d_out, (double*)d_ws);
}